// Round 9
// baseline (221.389 us; speedup 1.0000x reference)
//
#include <hip/hip_runtime.h>
#include <math.h>

#define T_LEN 4096
#define NTHR  512
#define NWAVE (NTHR / 64)
#define CHUNK 2
#define SEG   (NTHR * CHUNK)      // 1024 timesteps per block
#define NSEG  (T_LEN / SEG)       // 4 segments (blocks) per sample

typedef float f32x4 __attribute__((ext_vector_type(4)));

// Rotation for one step, via exp(skew(w*dt)) with even polynomials in theta^2.
// theta = |w|*dt <= ~0.04 for this input distribution; truncation ~1e-13 rel.
// No sqrt, no divide, no sin/cos.
__device__ __forceinline__ void make_A(float wx, float wy, float wz, float* A) {
    const float dt  = 1.0f / 200.0f;
    const float dt2 = dt * dt;
    float n2 = wx*wx + wy*wy + wz*wz;
    float t2 = n2 * dt2;                                   // theta^2
    float s_ = dt  * (1.0f + t2 * (-1.0f/6.0f  + t2 * (1.0f/120.0f)));
    float oc = dt2 * (0.5f + t2 * (-1.0f/24.0f + t2 * (1.0f/720.0f)));
    float xx = wx*wx, yy = wy*wy, zz = wz*wz;
    float xy = wx*wy, xz = wx*wz, yz = wy*wz;
    A[0] = 1.0f - oc*(yy+zz);
    A[1] = -s_*wz + oc*xy;
    A[2] =  s_*wy + oc*xz;
    A[3] =  s_*wz + oc*xy;
    A[4] = 1.0f - oc*(xx+zz);
    A[5] = -s_*wx + oc*yz;
    A[6] = -s_*wy + oc*xz;
    A[7] =  s_*wx + oc*yz;
    A[8] = 1.0f - oc*(xx+yy);
}

__device__ __forceinline__ void matmul3(const float* R, const float* A, float* N) {
#pragma unroll
    for (int i = 0; i < 3; ++i) {
        N[i*3+0] = R[i*3+0]*A[0] + R[i*3+1]*A[3] + R[i*3+2]*A[6];
        N[i*3+1] = R[i*3+0]*A[1] + R[i*3+1]*A[4] + R[i*3+2]*A[7];
        N[i*3+2] = R[i*3+0]*A[2] + R[i*3+1]*A[5] + R[i*3+2]*A[8];
    }
}

// One reference step applied to packed state E = [R(9), v(3), p(3)].
__device__ __forceinline__ void step(float* E, float wx, float wy, float wz,
                                     float ax, float ay, float az) {
    const float dt   = 1.0f / 200.0f;
    const float dt2h = dt * dt * 0.5f;
    float A[9], N[9];
    make_A(wx, wy, wz, A);
    matmul3(E, A, N);
#pragma unroll
    for (int i = 0; i < 9; ++i) E[i] = N[i];
    float rax = E[0]*ax + E[1]*ay + E[2]*az;
    float ray = E[3]*ax + E[4]*ay + E[5]*az;
    float raz = E[6]*ax + E[7]*ay + E[8]*az;
    E[9]  += rax*dt; E[10] += ray*dt; E[11] += raz*dt;
    E[12] += E[9]*dt  + rax*dt2h;
    E[13] += E[10]*dt + ray*dt2h;
    E[14] += E[11]*dt + raz*dt2h;
}

// e := L ∘ e   (L is the EARLIER segment; tauY = duration of e's segment)
//   A = L.A @ e.A ; b = L.b + L.A @ e.b ; c = L.c + tauY*L.b + L.A @ e.c
__device__ __forceinline__ void compose(const float* __restrict__ L,
                                        float* __restrict__ e, float tauY) {
    float N[9];
    matmul3(L, e, N);
    float b0 = L[9]  + L[0]*e[9] + L[1]*e[10] + L[2]*e[11];
    float b1 = L[10] + L[3]*e[9] + L[4]*e[10] + L[5]*e[11];
    float b2 = L[11] + L[6]*e[9] + L[7]*e[10] + L[8]*e[11];
    float c0 = L[12] + tauY*L[9]  + L[0]*e[12] + L[1]*e[13] + L[2]*e[14];
    float c1 = L[13] + tauY*L[10] + L[3]*e[12] + L[4]*e[13] + L[5]*e[14];
    float c2 = L[14] + tauY*L[11] + L[6]*e[12] + L[7]*e[13] + L[8]*e[14];
#pragma unroll
    for (int i = 0; i < 9; ++i) e[i] = N[i];
    e[9]  = b0; e[10] = b1; e[11] = b2;
    e[12] = c0; e[13] = c1; e[14] = c2;
}

// Quaternion from rotation matrix (matches reference acos/sin path + clip).
__device__ __forceinline__ float4 quat_of(const float* S) {
    float tr = S[0] + S[4] + S[8];
    float ca = fminf(fmaxf(0.5f * (tr - 1.0f), -1.0f + 1e-7f), 1.0f - 1e-7f);
    float x  = 0.5f * (1.0f + ca);
    float r  = __frsqrt_rn(x);
    float qw = x * r;                 // sqrt(x)
    float i4 = 0.25f * r;             // 0.25 / qw
    return make_float4(qw, (S[7] - S[5]) * i4,
                           (S[2] - S[6]) * i4,
                           (S[3] - S[1]) * i4);
}

// ---------------------------------------------------------------------------
// K1: per-segment totals. Block g = (sample b, segment s) integrates its
// 1024 steps (2 per thread) and writes the 15-float segment transform to ws.
// ---------------------------------------------------------------------------
__global__ __launch_bounds__(NTHR)
void totals_kernel(const float* __restrict__ in, float* __restrict__ ws) {
    const int g    = blockIdx.x;
    const int b    = g >> 2;            // NSEG == 4
    const int s    = g & (NSEG - 1);
    const int t    = threadIdx.x;
    const int lane = t & 63;
    const int w    = t >> 6;
    const float dt = 1.0f / 200.0f;

    const float4* src4 = (const float4*)(in +
        ((size_t)b * T_LEN + (size_t)s * SEG + (size_t)t * CHUNK) * 6);
    float4 u0 = src4[0], u1 = src4[1], u2 = src4[2];

    float e[15] = {1,0,0, 0,1,0, 0,0,1, 0,0,0, 0,0,0};
    step(e, u0.x, u0.y, u0.z, u0.w, u1.x, u1.y);
    step(e, u1.z, u1.w, u2.x, u2.y, u2.z, u2.w);

    // wave scan (total at lane 63)
#pragma unroll
    for (int d = 1; d < 64; d <<= 1) {
        float L[15];
#pragma unroll
        for (int i = 0; i < 15; ++i) L[i] = __shfl_up(e[i], d, 64);
        if (lane >= d) compose(L, e, (float)(d * CHUNK) * dt);
    }

    __shared__ float wtot[NWAVE * 15];
    if (lane == 63) {
#pragma unroll
        for (int i = 0; i < 15; ++i) wtot[w*15 + i] = e[i];
    }
    __syncthreads();

    if (w == 0) {
        float sv[15] = {1,0,0, 0,1,0, 0,0,1, 0,0,0, 0,0,0};
        if (lane < NWAVE) {
#pragma unroll
            for (int i = 0; i < 15; ++i) sv[i] = wtot[lane*15 + i];
        }
#pragma unroll
        for (int d = 1; d < NWAVE; d <<= 1) {
            float L[15];
#pragma unroll
            for (int i = 0; i < 15; ++i) L[i] = __shfl_up(sv[i], d, 64);
            if (lane >= d && lane < NWAVE)
                compose(L, sv, (float)(d * 64 * CHUNK) * dt);
        }
        if (lane == NWAVE - 1) {       // block total
#pragma unroll
            for (int i = 0; i < 15; ++i) ws[(size_t)g * 15 + i] = sv[i];
        }
    }
}

// ---------------------------------------------------------------------------
// K3: scan-and-emit. Same segmentation; internal block scan (2 serial steps),
// compose <=3 predecessor segment totals from ws, replay 2 steps, emit via
// the LDS full-line store transpose (R8).
// ---------------------------------------------------------------------------
__global__ __launch_bounds__(NTHR, 2)
void emit_kernel(const float* __restrict__ in, const float* __restrict__ ws,
                 float* __restrict__ out) {
    const int g    = blockIdx.x;
    const int b    = g >> 2;
    const int s    = g & (NSEG - 1);
    const int t    = threadIdx.x;
    const int lane = t & 63;
    const int w    = t >> 6;
    const float dt = 1.0f / 200.0f;

    const float4* src4 = (const float4*)(in +
        ((size_t)b * T_LEN + (size_t)s * SEG + (size_t)t * CHUNK) * 6);
    // 12 input floats — small enough to KEEP across the scan (no reload,
    // no spill: R2's spill was at 48 floats).
    float4 u0 = src4[0], u1 = src4[1], u2 = src4[2];

    // 64 KB staging tile (8 KB per wave, wave-private). First 480 B double as
    // wtot; all wtot reads finish before the barrier preceding tile writes.
    __shared__ __align__(16) float4 tile[NTHR * 8];
    float* wtot = (float*)tile;

    // ---- per-thread chunk aggregate ----
    float e[15] = {1,0,0, 0,1,0, 0,0,1, 0,0,0, 0,0,0};
    step(e, u0.x, u0.y, u0.z, u0.w, u1.x, u1.y);
    step(e, u1.z, u1.w, u2.x, u2.y, u2.z, u2.w);

    // ---- wave-level inclusive scan ----
#pragma unroll
    for (int d = 1; d < 64; d <<= 1) {
        float L[15];
#pragma unroll
        for (int i = 0; i < 15; ++i) L[i] = __shfl_up(e[i], d, 64);
        if (lane >= d) compose(L, e, (float)(d * CHUNK) * dt);
    }

    // ---- scan the 8 wave totals ----
    if (lane == 63) {
#pragma unroll
        for (int i = 0; i < 15; ++i) wtot[w*15 + i] = e[i];
    }
    __syncthreads();

    if (w == 0) {
        float sv[15] = {1,0,0, 0,1,0, 0,0,1, 0,0,0, 0,0,0};
        if (lane < NWAVE) {
#pragma unroll
            for (int i = 0; i < 15; ++i) sv[i] = wtot[lane*15 + i];
        }
#pragma unroll
        for (int d = 1; d < NWAVE; d <<= 1) {
            float L[15];
#pragma unroll
            for (int i = 0; i < 15; ++i) L[i] = __shfl_up(sv[i], d, 64);
            if (lane >= d && lane < NWAVE)
                compose(L, sv, (float)(d * 64 * CHUNK) * dt);
        }
        if (lane < NWAVE) {
#pragma unroll
            for (int i = 0; i < 15; ++i) wtot[lane*15 + i] = sv[i];
        }
    }
    __syncthreads();

    // ---- exclusive prefix within block ----
    float st[15];
#pragma unroll
    for (int i = 0; i < 15; ++i) st[i] = __shfl_up(e[i], 1, 64);
    if (lane == 0) {
        st[0]=1; st[1]=0; st[2]=0; st[3]=0; st[4]=1; st[5]=0;
        st[6]=0; st[7]=0; st[8]=1; st[9]=0; st[10]=0; st[11]=0;
        st[12]=0; st[13]=0; st[14]=0;
    }
    {
        float P[15] = {1,0,0, 0,1,0, 0,0,1, 0,0,0, 0,0,0};
        if (w > 0) {
#pragma unroll
            for (int i = 0; i < 15; ++i) P[i] = wtot[(w-1)*15 + i];
        }
        compose(P, st, (float)(lane * CHUNK) * dt);  // lane 0: tau=0 -> st = P
    }
    __syncthreads();   // wtot reads done; tile may now be overwritten

    // ---- fold in predecessor segment totals (<=3 composes, block-uniform) ----
    {
        float P0[15] = {1,0,0, 0,1,0, 0,0,1, 0,0,0, 0,0,0};
#pragma unroll
        for (int k = 0; k < NSEG - 1; ++k) {
            if (k < s) {
                float tmp[15];
                const float* Tk = ws + (size_t)(g - s + k) * 15;
#pragma unroll
                for (int i = 0; i < 15; ++i) tmp[i] = Tk[i];
                compose(P0, tmp, (float)SEG * dt);
#pragma unroll
                for (int i = 0; i < 15; ++i) P0[i] = tmp[i];
            }
        }
        // st covers t*CHUNK steps (exclusive within block)
        compose(P0, st, (float)(t * CHUNK) * dt);
    }

    // ---- replay 2 steps; stage in wave-private LDS; full-line store out ----
    float4* wt  = tile + (size_t)w * 512;   // this wave's 8 KB
    const int swz = lane & 7;

    step(st, u0.x, u0.y, u0.z, u0.w, u1.x, u1.y);
    {
        float4 q = quat_of(st);
        wt[(lane*8 + 0) ^ swz] = make_float4(u0.x, u0.y, u0.z, u0.w);
        wt[(lane*8 + 1) ^ swz] = make_float4(u1.x, u1.y, st[12], st[13]);
        wt[(lane*8 + 2) ^ swz] = make_float4(st[14], q.x, q.y, q.z);
        wt[(lane*8 + 3) ^ swz] = make_float4(q.w, st[9], st[10], st[11]);
    }
    step(st, u1.z, u1.w, u2.x, u2.y, u2.z, u2.w);
    {
        float4 q = quat_of(st);
        wt[(lane*8 + 4) ^ swz] = make_float4(u1.z, u1.w, u2.x, u2.y);
        wt[(lane*8 + 5) ^ swz] = make_float4(u2.z, u2.w, st[12], st[13]);
        wt[(lane*8 + 6) ^ swz] = make_float4(st[14], q.x, q.y, q.z);
        wt[(lane*8 + 7) ^ swz] = make_float4(q.w, st[9], st[10], st[11]);
    }

    // wave-synchronous: drain LDS writes, then cooperative coalesced copy
    asm volatile("s_waitcnt lgkmcnt(0)" ::: "memory");
    __builtin_amdgcn_sched_barrier(0);

    f32x4* go4 = (f32x4*)(out + ((size_t)b * T_LEN + (size_t)s * SEG) * 16)
                 + (size_t)w * 512;
#pragma unroll
    for (int i = 0; i < 8; ++i) {
        int c = i*64 + lane;                  // lanes 0-7 = one full 128B line
        float4 v = wt[c ^ ((c >> 3) & 7)];
        f32x4 vv = { v.x, v.y, v.z, v.w };
        __builtin_nontemporal_store(vv, &go4[c]);
    }
}

extern "C" void kernel_launch(void* const* d_in, const int* in_sizes, int n_in,
                              void* d_out, int out_size, void* d_ws, size_t ws_size,
                              hipStream_t stream) {
    const float* in = (const float*)d_in[0];
    float* out = (float*)d_out;
    float* ws  = (float*)d_ws;
    const int B = in_sizes[0] / (T_LEN * 6);   // 512
    totals_kernel<<<dim3(B * NSEG), dim3(NTHR), 0, stream>>>(in, ws);
    emit_kernel<<<dim3(B * NSEG), dim3(NTHR), 0, stream>>>(in, ws, out);
}

// Round 10
// 182.573 us; speedup vs baseline: 1.2126x; 1.2126x over previous
//
#include <hip/hip_runtime.h>
#include <math.h>

#define T_LEN 4096
#define CHUNK 8
#define NTHR  512
#define NWAVE (NTHR / 64)

typedef float f32x4 __attribute__((ext_vector_type(4)));

// Rotation for one step, via exp(skew(w*dt)) with even polynomials in theta^2.
// theta = |w|*dt <= ~0.04 for this input distribution; truncation ~1e-13 rel.
// No sqrt, no divide, no sin/cos.
__device__ __forceinline__ void make_A(float wx, float wy, float wz, float* A) {
    const float dt  = 1.0f / 200.0f;
    const float dt2 = dt * dt;
    float n2 = wx*wx + wy*wy + wz*wz;
    float t2 = n2 * dt2;                                   // theta^2
    float s_ = dt  * (1.0f + t2 * (-1.0f/6.0f  + t2 * (1.0f/120.0f)));
    float oc = dt2 * (0.5f + t2 * (-1.0f/24.0f + t2 * (1.0f/720.0f)));
    float xx = wx*wx, yy = wy*wy, zz = wz*wz;
    float xy = wx*wy, xz = wx*wz, yz = wy*wz;
    A[0] = 1.0f - oc*(yy+zz);
    A[1] = -s_*wz + oc*xy;
    A[2] =  s_*wy + oc*xz;
    A[3] =  s_*wz + oc*xy;
    A[4] = 1.0f - oc*(xx+zz);
    A[5] = -s_*wx + oc*yz;
    A[6] = -s_*wy + oc*xz;
    A[7] =  s_*wx + oc*yz;
    A[8] = 1.0f - oc*(xx+yy);
}

__device__ __forceinline__ void matmul3(const float* R, const float* A, float* N) {
#pragma unroll
    for (int i = 0; i < 3; ++i) {
        N[i*3+0] = R[i*3+0]*A[0] + R[i*3+1]*A[3] + R[i*3+2]*A[6];
        N[i*3+1] = R[i*3+0]*A[1] + R[i*3+1]*A[4] + R[i*3+2]*A[7];
        N[i*3+2] = R[i*3+0]*A[2] + R[i*3+1]*A[5] + R[i*3+2]*A[8];
    }
}

// One reference step applied to packed state E = [R(9), v(3), p(3)].
__device__ __forceinline__ void step(float* E, float wx, float wy, float wz,
                                     float ax, float ay, float az) {
    const float dt   = 1.0f / 200.0f;
    const float dt2h = dt * dt * 0.5f;
    float A[9], N[9];
    make_A(wx, wy, wz, A);
    matmul3(E, A, N);
#pragma unroll
    for (int i = 0; i < 9; ++i) E[i] = N[i];
    float rax = E[0]*ax + E[1]*ay + E[2]*az;
    float ray = E[3]*ax + E[4]*ay + E[5]*az;
    float raz = E[6]*ax + E[7]*ay + E[8]*az;
    E[9]  += rax*dt; E[10] += ray*dt; E[11] += raz*dt;
    E[12] += E[9]*dt  + rax*dt2h;
    E[13] += E[10]*dt + ray*dt2h;
    E[14] += E[11]*dt + raz*dt2h;
}

// e := L ∘ e   (L is the EARLIER segment; tauY = duration of e's segment)
__device__ __forceinline__ void compose(const float* __restrict__ L,
                                        float* __restrict__ e, float tauY) {
    float N[9];
    matmul3(L, e, N);
    float b0 = L[9]  + L[0]*e[9] + L[1]*e[10] + L[2]*e[11];
    float b1 = L[10] + L[3]*e[9] + L[4]*e[10] + L[5]*e[11];
    float b2 = L[11] + L[6]*e[9] + L[7]*e[10] + L[8]*e[11];
    float c0 = L[12] + tauY*L[9]  + L[0]*e[12] + L[1]*e[13] + L[2]*e[14];
    float c1 = L[13] + tauY*L[10] + L[3]*e[12] + L[4]*e[13] + L[5]*e[14];
    float c2 = L[14] + tauY*L[11] + L[6]*e[12] + L[7]*e[13] + L[8]*e[14];
#pragma unroll
    for (int i = 0; i < 9; ++i) e[i] = N[i];
    e[9]  = b0; e[10] = b1; e[11] = b2;
    e[12] = c0; e[13] = c1; e[14] = c2;
}

// Quaternion from rotation matrix (matches reference acos/sin path + clip).
__device__ __forceinline__ float4 quat_of(const float* S) {
    float tr = S[0] + S[4] + S[8];
    float ca = fminf(fmaxf(0.5f * (tr - 1.0f), -1.0f + 1e-7f), 1.0f - 1e-7f);
    float x  = 0.5f * (1.0f + ca);
    float r  = __frsqrt_rn(x);
    float qw = x * r;                 // sqrt(x)
    float i4 = 0.25f * r;             // 0.25 / qw
    return make_float4(qw, (S[7] - S[5]) * i4,
                           (S[2] - S[6]) * i4,
                           (S[3] - S[1]) * i4);
}

__global__ __launch_bounds__(NTHR, 2)
void preint_kernel(const float* __restrict__ in, float* __restrict__ out) {
    const int b    = blockIdx.x;
    const int t    = threadIdx.x;
    const int lane = t & 63;
    const int w    = t >> 6;
    const float dt = 1.0f / 200.0f;

    const float* bin  = in  + (size_t)b * T_LEN * 6;
    float*       bout = out + (size_t)b * T_LEN * 16;
    const float4* src4 = (const float4*)(bin + (size_t)t * CHUNK * 6);

    // 64 KB staging tile (8 KB per wave, wave-private => no barriers in the
    // phase-3 loop). First 480 B double as wtot for phase 2b.
    __shared__ __align__(16) float4 tile[NTHR * 8];     // 4096 float4 = 64 KB
    float* wtot = (float*)tile;                         // [NWAVE][15] overlay

    // ---- Phase 1: batch-issue ALL 12 input loads, then the 8-step chain ----
    // (R10: at VGPR=80 the compiler interleaved load->wait->2 steps per pp,
    // paying memory latency 4x serially. Batch + sched fence pins issue-all-
    // first; live range is phase-local so no spill.)
    float4 u[12];
#pragma unroll
    for (int i = 0; i < 12; ++i) u[i] = src4[i];
    __builtin_amdgcn_sched_barrier(0);

    float e[15] = {1,0,0, 0,1,0, 0,0,1, 0,0,0, 0,0,0};
#pragma unroll
    for (int pp = 0; pp < CHUNK / 2; ++pp) {
        float4 u0 = u[pp*3+0];
        float4 u1 = u[pp*3+1];
        float4 u2 = u[pp*3+2];
        step(e, u0.x, u0.y, u0.z, u0.w, u1.x, u1.y);
        step(e, u1.z, u1.w, u2.x, u2.y, u2.z, u2.w);
    }

    // ---- Phase 2a: wave-level inclusive scan (shuffles, no barriers) ----
#pragma unroll
    for (int d = 1; d < 64; d <<= 1) {
        float L[15];
#pragma unroll
        for (int i = 0; i < 15; ++i) L[i] = __shfl_up(e[i], d, 64);
        if (lane >= d) compose(L, e, (float)(d * CHUNK) * dt);
    }

    // ---- Phase 2b: scan the 8 wave totals ----
    if (lane == 63) {
#pragma unroll
        for (int i = 0; i < 15; ++i) wtot[w*15 + i] = e[i];
    }
    __syncthreads();

    if (w == 0) {
        float s[15] = {1,0,0, 0,1,0, 0,0,1, 0,0,0, 0,0,0};
        if (lane < NWAVE) {
#pragma unroll
            for (int i = 0; i < 15; ++i) s[i] = wtot[lane*15 + i];
        }
#pragma unroll
        for (int d = 1; d < NWAVE; d <<= 1) {
            float L[15];
#pragma unroll
            for (int i = 0; i < 15; ++i) L[i] = __shfl_up(s[i], d, 64);
            if (lane >= d && lane < NWAVE)
                compose(L, s, (float)(d * 64 * CHUNK) * dt);
        }
        if (lane < NWAVE) {
#pragma unroll
            for (int i = 0; i < 15; ++i) wtot[lane*15 + i] = s[i];
        }
    }
    __syncthreads();

    // ---- Exclusive-prefix state for this thread ----
    float st[15];
#pragma unroll
    for (int i = 0; i < 15; ++i) st[i] = __shfl_up(e[i], 1, 64);
    if (lane == 0) {
        st[0]=1; st[1]=0; st[2]=0; st[3]=0; st[4]=1; st[5]=0;
        st[6]=0; st[7]=0; st[8]=1; st[9]=0; st[10]=0; st[11]=0;
        st[12]=0; st[13]=0; st[14]=0;
    }
    {
        float P[15] = {1,0,0, 0,1,0, 0,0,1, 0,0,0, 0,0,0};
        if (w > 0) {
#pragma unroll
            for (int i = 0; i < 15; ++i) P[i] = wtot[(w-1)*15 + i];
        }
        compose(P, st, (float)(lane * CHUNK) * dt);  // lane 0: tau=0 -> st = P
    }
    __syncthreads();   // wtot reads done; tile region may now be overwritten

    // ---- Phase 3: batch-reload input (L2/L3-resident), replay, emit ----
    // Data-dep + fence: keeps the reloads AFTER the scan so the 48-float
    // input live range never spans it (R2/R3 spill lesson).
    const float4* src4b;
    {
        unsigned long long pbits = (unsigned long long)src4;
        asm volatile("" : "+v"(pbits) : "v"(st[0]), "v"(st[14]));
        src4b = (const float4*)pbits;
    }
    __builtin_amdgcn_sched_barrier(0);

    float4 v[12];
#pragma unroll
    for (int i = 0; i < 12; ++i) v[i] = src4b[i];
    __builtin_amdgcn_sched_barrier(0);

    float4* wt  = tile + (size_t)w * 512;              // this wave's 8 KB
    f32x4*  go4 = (f32x4*)bout + (size_t)w * 2048;     // this wave's 128 KB out
    const int swz = lane & 7;                          // writer swizzle key

#pragma unroll
    for (int pp = 0; pp < CHUNK / 2; ++pp) {
        float4 u0 = v[pp*3+0];
        float4 u1 = v[pp*3+1];
        float4 u2 = v[pp*3+2];

        // row j=0 (global row 8t + 2pp): LDS idx = (lane*8 + o) ^ (lane&7)
        step(st, u0.x, u0.y, u0.z, u0.w, u1.x, u1.y);
        {
            float4 q = quat_of(st);
            wt[(lane*8 + 0) ^ swz] = make_float4(u0.x, u0.y, u0.z, u0.w);
            wt[(lane*8 + 1) ^ swz] = make_float4(u1.x, u1.y, st[12], st[13]);
            wt[(lane*8 + 2) ^ swz] = make_float4(st[14], q.x, q.y, q.z);
            wt[(lane*8 + 3) ^ swz] = make_float4(q.w, st[9], st[10], st[11]);
        }

        // row j=1 (global row 8t + 2pp + 1)
        step(st, u1.z, u1.w, u2.x, u2.y, u2.z, u2.w);
        {
            float4 q = quat_of(st);
            wt[(lane*8 + 4) ^ swz] = make_float4(u1.z, u1.w, u2.x, u2.y);
            wt[(lane*8 + 5) ^ swz] = make_float4(u2.z, u2.w, st[12], st[13]);
            wt[(lane*8 + 6) ^ swz] = make_float4(st[14], q.x, q.y, q.z);
            wt[(lane*8 + 7) ^ swz] = make_float4(q.w, st[9], st[10], st[11]);
        }

        // Wave-synchronous: drain LDS writes, then cooperative coalesced copy.
        asm volatile("s_waitcnt lgkmcnt(0)" ::: "memory");
        __builtin_amdgcn_sched_barrier(0);

        // lanes 0-7 cover one full 128B line; 8 full lines per instruction.
#pragma unroll
        for (int i = 0; i < 8; ++i) {
            int c = i*64 + lane;
            float4 x = wt[c ^ ((c >> 3) & 7)];
            f32x4 vv = { x.x, x.y, x.z, x.w };
            int g = i*256 + (lane >> 3)*32 + pp*8 + (lane & 7);
            __builtin_nontemporal_store(vv, &go4[g]);
        }
        __builtin_amdgcn_sched_barrier(0);   // keep next pp's LDS writes below
    }
}

extern "C" void kernel_launch(void* const* d_in, const int* in_sizes, int n_in,
                              void* d_out, int out_size, void* d_ws, size_t ws_size,
                              hipStream_t stream) {
    const float* in = (const float*)d_in[0];
    float* out = (float*)d_out;
    const int B = in_sizes[0] / (T_LEN * 6);   // 512
    preint_kernel<<<dim3(B), dim3(NTHR), 0, stream>>>(in, out);
}